// Round 4
// baseline (171.752 us; speedup 1.0000x reference)
//
#include <hip/hip_runtime.h>
#include <hip/hip_bf16.h>
#include <cstdint>
#include <cstddef>

#define NA   2048
#define NB   2048
#define DD   512

typedef __attribute__((ext_vector_type(8))) short bf16x8;
typedef __attribute__((ext_vector_type(4))) float f32x4;
typedef unsigned short u16;
typedef unsigned int   u32;

__device__ __forceinline__ u16 f2b_hw(float f) {
    u32 w;
    asm("v_cvt_pk_bf16_f32 %0, %1, %2" : "=v"(w) : "v"(f), "v"(f));
    return (u16)w;
}
__device__ __forceinline__ float b2f(u16 h) {
    return __uint_as_float(((u32)h) << 16);
}
__device__ __forceinline__ u32 umin32(u32 a, u32 b) { return a < b ? a : b; }
__device__ __forceinline__ u32 umax32(u32 a, u32 b) { return a > b ? a : b; }
__device__ __forceinline__ u32 med3u(u32 a, u32 b, u32 c) {
    return umax32(umin32(a, b), umin32(umax32(a, b), c));   // -> v_med3_u32
}
__device__ __forceinline__ bf16x8 cvt8(f32x4 v0, f32x4 v1) {
    u32 w0, w1, w2, w3;
    asm("v_cvt_pk_bf16_f32 %0, %1, %2" : "=v"(w0) : "v"(v0[0]), "v"(v0[1]));
    asm("v_cvt_pk_bf16_f32 %0, %1, %2" : "=v"(w1) : "v"(v0[2]), "v"(v0[3]));
    asm("v_cvt_pk_bf16_f32 %0, %1, %2" : "=v"(w2) : "v"(v1[0]), "v"(v1[1]));
    asm("v_cvt_pk_bf16_f32 %0, %1, %2" : "=v"(w3) : "v"(v1[2]), "v"(v1[3]));
    union { u32 u[4]; bf16x8 v; } cv;
    cv.u[0] = w0; cv.u[1] = w1; cv.u[2] = w2; cv.u[3] = w3;
    return cv.v;
}

#define GLDS16(gsrc, ldst)                                                  \
    __builtin_amdgcn_global_load_lds(                                       \
        (const __attribute__((address_space(1))) void*)(gsrc),              \
        (__attribute__((address_space(3))) void*)(ldst), 16, 0, 0)

// ---------------------------------------------------------------------------
// Coalesced LDS-transpose: W2T[n][k]=W[512+k][n], WdT[n][k]=W[k][n]-W[512+k][n]
// ---------------------------------------------------------------------------
__global__ __launch_bounds__(256) void prep_w(const float* __restrict__ W,
                                              u16* __restrict__ W2T,
                                              u16* __restrict__ WdT) {
    __shared__ float s2[64][65];
    __shared__ float sd[64][65];
    int kb = blockIdx.x * 64, nb = blockIdx.y * 64;
    int tid = threadIdx.x;
    int c = tid & 63, r0 = tid >> 6;
    #pragma unroll
    for (int p = 0; p < 16; ++p) {
        int r = p * 4 + r0;
        float w1 = W[(size_t)(kb + r) * DD + nb + c];
        float w2 = W[(size_t)(512 + kb + r) * DD + nb + c];
        s2[r][c] = w2;
        sd[r][c] = w1 - w2;
    }
    __syncthreads();
    #pragma unroll
    for (int p = 0; p < 16; ++p) {
        int n = p * 4 + r0;
        W2T[(size_t)(nb + n) * DD + kb + c] = f2b_hw(s2[c][n]);
        WdT[(size_t)(nb + n) * DD + kb + c] = f2b_hw(sd[c][n]);
    }
}

// ---------------------------------------------------------------------------
// Streaming pre-pass: fa -> out[:,0:512] (f32) + Ab (bf16); fb -> Bb (bf16)
// ---------------------------------------------------------------------------
__global__ __launch_bounds__(256) void convert_kernel(const float* __restrict__ fa,
                                                      const float* __restrict__ fb,
                                                      u16* __restrict__ Ab,
                                                      u16* __restrict__ Bb,
                                                      float* __restrict__ out) {
    const int nthreads = 2048 * 256;
    int t = blockIdx.x * 256 + threadIdx.x;
    // fa: 32768 rows x 64 segments of 8 floats
    for (int s = t; s < 32768 * 64; s += nthreads) {
        int row = s >> 6, c8 = (s & 63) << 3;
        const float* src = fa + ((size_t)row << 9) + c8;
        f32x4 v0 = *(const f32x4*)src;
        f32x4 v1 = *(const f32x4*)(src + 4);
        float* d = out + ((size_t)row << 10) + c8;
        *(f32x4*)d = v0;
        *(f32x4*)(d + 4) = v1;
        *(bf16x8*)(Ab + ((size_t)row << 9) + c8) = cvt8(v0, v1);
    }
    for (int s = t; s < 32768 * 64; s += nthreads) {
        int row = s >> 6, c8 = (s & 63) << 3;
        const float* src = fb + ((size_t)row << 9) + c8;
        f32x4 v0 = *(const f32x4*)src;
        f32x4 v1 = *(const f32x4*)(src + 4);
        *(bf16x8*)(Bb + ((size_t)row << 9) + c8) = cvt8(v0, v1);
    }
}

// ---------------------------------------------------------------------------
// Exact integer top-4 NN (lax.top_k tie-break). key=(s<<11)|j.
// ---------------------------------------------------------------------------
__global__ __launch_bounds__(512) void topk_kernel(const int* __restrict__ ca,
                                                   const int* __restrict__ cb,
                                                   int* __restrict__ idx_out,
                                                   float* __restrict__ w_out) {
    __shared__ u32 pcb[NB];            // packed coords, 8KB
    __shared__ u32 part[3 * 128 * 4];  // partial top-4 of groups 1..3, 6KB
    int b = blockIdx.y;
    int tid = threadIdx.x;
    for (int p = tid; p < NB; p += 512) {
        const int* c = cb + ((size_t)b * NB + p) * 3;
        pcb[p] = (u32)c[0] | ((u32)c[1] << 8) | ((u32)c[2] << 16);
    }
    __syncthreads();

    int q = tid & 127, g = tid >> 7;
    int i = blockIdx.x * 128 + q;
    const int* ac = ca + ((size_t)b * NA + i) * 3;
    int ax = ac[0], ay = ac[1], az = ac[2];

    u32 k0 = ~0u, k1 = ~0u, k2 = ~0u, k3 = ~0u;
    int j0 = g * 512;
    #pragma unroll 8
    for (int jj = 0; jj < 512; ++jj) {
        int j = j0 + jj;
        u32 p = pcb[j];
        int dx = ax - (int)(p & 255u);
        int dy = ay - (int)((p >> 8) & 255u);
        int dz = az - (int)(p >> 16);
        u32 s = (u32)(__mul24(dx, dx) + __mul24(dy, dy) + __mul24(dz, dz));
        u32 key = (s << 11) | (u32)j;
        u32 nk0 = umin32(k0, key);
        u32 nk1 = med3u(key, k0, k1);
        u32 nk2 = med3u(key, k1, k2);
        u32 nk3 = med3u(key, k2, k3);
        k0 = nk0; k1 = nk1; k2 = nk2; k3 = nk3;
    }
    if (g) {
        u32* pp = &part[((g - 1) * 128 + q) * 4];
        pp[0] = k0; pp[1] = k1; pp[2] = k2; pp[3] = k3;
    }
    __syncthreads();
    if (g == 0) {
        #pragma unroll
        for (int L = 0; L < 3; ++L) {
            const u32* pp = &part[(L * 128 + q) * 4];
            #pragma unroll
            for (int t = 0; t < 4; ++t) {
                u32 key = pp[t];
                u32 nk0 = umin32(k0, key);
                u32 nk1 = med3u(key, k0, k1);
                u32 nk2 = med3u(key, k1, k2);
                u32 nk3 = med3u(key, k2, k3);
                k0 = nk0; k1 = nk1; k2 = nk2; k3 = nk3;
            }
        }
        size_t o = ((size_t)b * NA + i) * 4;
        u32 ks[4] = {k0, k1, k2, k3};
        #pragma unroll
        for (int t = 0; t < 4; ++t) {
            idx_out[o + t] = (int)(ks[t] & 2047u);
            float d = sqrtf((float)(ks[t] >> 11)) * (1.0f / 128.0f);
            w_out[o + t] = 0.5f - fminf(d, 0.5f);
        }
    }
}

// ---------------------------------------------------------------------------
// C = A @ BT^T, both bf16, m97 structure: GLDS16 both operands, linear LDS
// [128][32], 8 ds_read_b128 + 16 MFMA per K-step.
// FUSED: no C write; bias+relu-gather epilogue writes out[:,512+n0..+128).
// XCD-bijective m-swizzle (8x32) keeps each XCD's rows = 2 batches.
// ---------------------------------------------------------------------------
template<bool FUSED>
__global__ __launch_bounds__(256) void gemm_kernel(const u16* __restrict__ A,
                                                   const u16* __restrict__ BT,
                                                   u16* __restrict__ C,
                                                   const int* __restrict__ idxb,
                                                   const float* __restrict__ wb,
                                                   const float* __restrict__ bias,
                                                   const u16* __restrict__ Qb,
                                                   float* __restrict__ out) {
    __shared__ __align__(16) char smem[FUSED ? 33792 : 16384];
    u16* As = (u16*)smem;                     // [128][32] bf16, 8 KB
    u16* Bs = (u16*)(smem + 8192);            // [128][32] bf16, 8 KB

    const int tid  = threadIdx.x;
    const int lane = tid & 63;
    const int wave = tid >> 6;
    const int mb   = blockIdx.x;
    const int m0 = (((mb & 7) << 5) | (mb >> 3)) * 128;   // bijective 8x32
    const int n0 = blockIdx.y * 128;
    const int l15 = lane & 15;
    const int lk8 = (lane >> 4) * 8;

    const int srow = lane >> 2;      // 0..15 row within 16-row stage group
    const int scol = (lane & 3) * 8; // bf16 col offset of 16B chunk

    const int wr = (wave >> 1) * 64;
    const int wc = (wave & 1) * 64;

    f32x4 acc[4][4];
    #pragma unroll
    for (int m = 0; m < 4; ++m)
        #pragma unroll
        for (int n = 0; n < 4; ++n)
            acc[m][n] = (f32x4){0.f, 0.f, 0.f, 0.f};

    const u16* asrc[2];
    const u16* bsrc[2];
    #pragma unroll
    for (int p = 0; p < 2; ++p) {
        asrc[p] = A  + (size_t)(m0 + wave * 32 + p * 16 + srow) * DD + scol;
        bsrc[p] = BT + (size_t)(n0 + wave * 32 + p * 16 + srow) * DD + scol;
    }

    for (int kk = 0; kk < DD; kk += 32) {
        #pragma unroll
        for (int p = 0; p < 2; ++p) {
            GLDS16(asrc[p] + kk, As + wave * 1024 + p * 512);
            GLDS16(bsrc[p] + kk, Bs + wave * 1024 + p * 512);
        }
        __syncthreads();

        bf16x8 af[4], bfr[4];
        #pragma unroll
        for (int m = 0; m < 4; ++m)
            af[m] = *(const bf16x8*)(&As[(wr + m * 16 + l15) * 32 + lk8]);
        #pragma unroll
        for (int n = 0; n < 4; ++n)
            bfr[n] = *(const bf16x8*)(&Bs[(wc + n * 16 + l15) * 32 + lk8]);

        #pragma unroll
        for (int m = 0; m < 4; ++m)
            #pragma unroll
            for (int n = 0; n < 4; ++n)
                acc[m][n] = __builtin_amdgcn_mfma_f32_16x16x32_bf16(
                    af[m], bfr[n], acc[m][n], 0, 0, 0);
        __syncthreads();
    }

    const int r4 = (lane >> 4) * 4;

    if (!FUSED) {
        #pragma unroll
        for (int m = 0; m < 4; ++m)
            #pragma unroll
            for (int n = 0; n < 4; ++n)
                #pragma unroll
                for (int j = 0; j < 4; ++j) {
                    int row = m0 + wr + m * 16 + r4 + j;
                    int col = n0 + wc + n * 16 + l15;
                    C[(size_t)row * DD + col] = f2b_hw(acc[m][n][j]);
                }
        return;
    }

    // ---- fused epilogue: P' = acc + bias -> LDS (bf16), then gather+out ----
    float bi[4];
    #pragma unroll
    for (int n = 0; n < 4; ++n)
        bi[n] = bias[n0 + wc + n * 16 + l15];

    u16* Ps = (u16*)smem;                     // [128][132] bf16, 33 KB
    __syncthreads();
    #pragma unroll
    for (int m = 0; m < 4; ++m)
        #pragma unroll
        for (int n = 0; n < 4; ++n)
            #pragma unroll
            for (int j = 0; j < 4; ++j)
                Ps[(wr + m * 16 + r4 + j) * 132 + (wc + n * 16 + l15)] =
                    f2b_hw(acc[m][n][j] + bi[n]);
    __syncthreads();

    const int g = tid >> 4, l16 = tid & 15;
    const int bb = m0 >> 11;                                  // batch
    const u16* qs = Qb + ((size_t)bb << 20);                  // b*2048*512
    #pragma unroll
    for (int k = 0; k < 8; ++k) {
        const int r  = g * 8 + k;
        const int gr = m0 + r;
        int4  iv = *(const int4*)(idxb + (size_t)gr * 4);
        f32x4 wv = *(const f32x4*)(wb + (size_t)gr * 4);
        bf16x8 p8 = *(const bf16x8*)(Ps + r * 132 + l16 * 8);
        bf16x8 q0 = *(const bf16x8*)(qs + (size_t)iv.x * DD + n0 + l16 * 8);
        bf16x8 q1 = *(const bf16x8*)(qs + (size_t)iv.y * DD + n0 + l16 * 8);
        bf16x8 q2 = *(const bf16x8*)(qs + (size_t)iv.z * DD + n0 + l16 * 8);
        bf16x8 q3 = *(const bf16x8*)(qs + (size_t)iv.w * DD + n0 + l16 * 8);
        float o[8];
        #pragma unroll
        for (int j = 0; j < 8; ++j) {
            float p = b2f((u16)p8[j]);
            float s;
            s  = fmaxf(p + b2f((u16)q0[j]), 0.f) * wv[0];
            s += fmaxf(p + b2f((u16)q1[j]), 0.f) * wv[1];
            s += fmaxf(p + b2f((u16)q2[j]), 0.f) * wv[2];
            s += fmaxf(p + b2f((u16)q3[j]), 0.f) * wv[3];
            o[j] = s;
        }
        float* op = out + (size_t)gr * 1024 + 512 + n0 + l16 * 8;
        *(f32x4*)op       = (f32x4){o[0], o[1], o[2], o[3]};
        *(f32x4*)(op + 4) = (f32x4){o[4], o[5], o[6], o[7]};
    }
}

extern "C" void kernel_launch(void* const* d_in, const int* in_sizes, int n_in,
                              void* d_out, int out_size, void* d_ws, size_t ws_size,
                              hipStream_t stream) {
    const float* fa   = (const float*)d_in[0];
    const float* fb   = (const float*)d_in[1];
    const float* W    = (const float*)d_in[2];
    const float* bias = (const float*)d_in[3];
    const int*   ca   = (const int*)d_in[4];
    const int*   cb   = (const int*)d_in[5];
    float* out = (float*)d_out;

    char* ws = (char*)d_ws;
    u16*   Qb   = (u16*)(ws);                       // 32 MB bf16 Q
    u16*   Ab   = (u16*)(ws + 33554432);            // 32 MB bf16 fa
    u16*   Bb   = (u16*)(ws + 67108864);            // 32 MB bf16 fb
    u16*   W2T  = (u16*)(ws + 100663296);           // 512 KB
    u16*   WdT  = (u16*)(ws + 101187584);           // 512 KB
    int*   idxb = (int*)(ws + 101711872);           // 512 KB
    float* wb   = (float*)(ws + 102236160);         // 512 KB

    dim3 pg(8, 8);
    prep_w<<<pg, 256, 0, stream>>>(W, W2T, WdT);

    dim3 tg(16, 16);
    topk_kernel<<<tg, 512, 0, stream>>>(ca, cb, idxb, wb);

    convert_kernel<<<2048, 256, 0, stream>>>(fa, fb, Ab, Bb, out);

    dim3 gg(256, 4);
    gemm_kernel<false><<<gg, 256, 0, stream>>>(Bb, WdT, Qb, nullptr, nullptr,
                                               nullptr, nullptr, nullptr);
    gemm_kernel<true><<<gg, 256, 0, stream>>>(Ab, W2T, nullptr, idxb, wb,
                                              bias, Qb, out);
}